// Round 1
// 457.087 us; speedup vs baseline: 1.1292x; 1.1292x over previous
//
#include <hip/hip_runtime.h>
#include <stdint.h>

typedef unsigned short u16;
typedef __attribute__((ext_vector_type(8))) short bf16x8;      // 8 bf16 = 4 VGPRs
typedef __attribute__((ext_vector_type(8))) unsigned short u16x8;
typedef __attribute__((ext_vector_type(4))) float f32x4;

#define B_  2
#define T_  4096
#define C_  2048
#define NH  16
#define NKV 4
#define HD  128

__device__ __forceinline__ u16 f2bf(float f) {
  union { float f; uint32_t u; } v; v.f = f;
  uint32_t u = v.u;
  u += 0x7fffu + ((u >> 16) & 1u);   // RNE
  return (u16)(u >> 16);
}
__device__ __forceinline__ float bf2f(u16 h) {
  union { uint32_t u; float f; } v; v.u = ((uint32_t)h) << 16;
  return v.f;
}

__device__ __forceinline__ void gload_lds16(const u16* g, u16* l) {
  __builtin_amdgcn_global_load_lds(
      (const __attribute__((address_space(1))) void*)g,
      (__attribute__((address_space(3))) void*)l, 16, 0, 0);
}

// ---------------- f32 -> bf16 convert ----------------
__global__ void cvt_f32_bf16(const float* __restrict__ src, u16* __restrict__ dst, int n) {
  int i = (blockIdx.x * blockDim.x + threadIdx.x) * 4;
  if (i >= n) return;
  float4 v = *(const float4*)(src + i);
  ushort4 o;
  o.x = f2bf(v.x); o.y = f2bf(v.y); o.z = f2bf(v.z); o.w = f2bf(v.w);
  *(ushort4*)(dst + i) = o;
}

// ---------------- in-place RoPE on qkv [B*T][3072]; Q pre-scaled by 1/sqrt(D)*log2e ----------------
__global__ void rope_kernel(u16* __restrict__ qkv, const float* __restrict__ cache) {
  const int PH = (NH + NKV) * (HD / 2);   // 1280 pairs per row
  long idx = (long)blockIdx.x * blockDim.x + threadIdx.x;
  if (idx >= (long)B_ * T_ * PH) return;
  int row = (int)(idx / PH);
  int rem = (int)(idx % PH);
  int hh = rem >> 6;
  int i  = rem & 63;
  int t  = row & (T_ - 1);
  float sc = (hh < NH) ? 0.1275174315f : 1.0f;   // q heads: fold scale*log2(e)
  float c = cache[t * 128 + 2 * i] * sc;
  float s = cache[t * 128 + 2 * i + 1] * sc;
  u16* p = qkv + (long)row * 3072 + hh * HD + 2 * i;
  float x0 = bf2f(p[0]), x1 = bf2f(p[1]);
  p[0] = f2bf(x0 * c - x1 * s);
  p[1] = f2bf(x0 * s + x1 * c);
}

// ---------------- K rearrange: frag-linear layout ----------------
// K2[bk][kb=key/16][ks=d/32][q4][l16=key%16][e=d%8]
__global__ void krearr(const u16* __restrict__ qkv, u16* __restrict__ K2) {
  int gid = blockIdx.x * 256 + threadIdx.x;
  int r = gid & 65535, bk = gid >> 16;
  int l16 = r & 15, q4 = (r >> 4) & 3, ks = (r >> 6) & 3, kb = r >> 8;
  int bb = bk >> 2, kv = bk & 3;
  const u16* src = qkv + ((long)(bb * T_ + kb * 16 + l16)) * 3072 + 2048 + kv * HD +
                   ks * 32 + q4 * 8;
  *(u16x8*)(K2 + (long)bk * 524288 + (long)r * 8) = *(const u16x8*)src;
}

// ---------------- V rearrange: frag-linear transposed layout ----------------
// V2[bk][kc=key/128][jd=d/16][ks=(key%128)/32][q4][l16=d%16][e=key%8]
__global__ void vrearr(const u16* __restrict__ qkv, u16* __restrict__ V2) {
  int gid = blockIdx.x * 256 + threadIdx.x;
  int r = gid & 65535, bk = gid >> 16;
  int l16 = r & 15, q4 = (r >> 4) & 3, ks = (r >> 6) & 3, jd = (r >> 8) & 7, kc = r >> 11;
  int bb = bk >> 2, kv = bk & 3;
  int key0 = kc * 128 + ks * 32 + q4 * 8;
  int d = jd * 16 + l16;
  const u16* src = qkv + ((long)(bb * T_ + key0)) * 3072 + 2560 + kv * HD + d;
  u16x8 v;
#pragma unroll
  for (int e = 0; e < 8; e++) v[e] = src[(long)e * 3072];
  *(u16x8*)(V2 + (long)bk * 524288 + (long)r * 8) = v;
}

// ---------------- bf16 GEMM: C[M][N] = A[M][K] * B[N][K]^T ----------------
// 256x256 tile, BK=64, 8 waves (2M x 4N), double-buffered 128 KiB LDS,
// 8-phase schedule per 2 K-tiles with counted vmcnt (never 0 in steady state),
// k-half staging with region-reuse, XOR LDS swizzle (2-way conflicts = free),
// setprio around MFMA clusters, bijective XCD-aware block swizzle.
//
// LDS layout (u16 units): [buf:2][mat:2][kh:2][row:256][32]
//   plane(buf,mat,kh) = buf*32768 + mat*16384 + kh*8192
//   element (row, col) stored at row*32 + (col XOR-swizzled):
//   linear slot s in row r holds source col-slot s ^ ((r>>1)&3)  (involution).
// Stage = one k-half of A or B (256 rows x 32 k = 16 KB): each of 512 threads
// issues 2 x global_load_lds dwordx4 at linear dest tid*16 (+8192).
//
// Per K-tile, 4 phases:
//   P1: ds_read A[m0-3]kh0 + B[n0-3]kh0 ; stage (kt+1, A-k1) ; bar ; 16 MFMA ; bar
//   P2: ds_read A[m4-7]kh0              ; stage (kt+1, B-k1) ; bar ; 16 MFMA ; bar
//   P3: ds_read A[m0-3]kh1 + B[n0-3]kh1 ; stage (kt+2, A-k0) ; bar ; 16 MFMA ; bar
//   P4: ds_read A[m4-7]kh1              ; stage (kt+2, B-k0) ; bar ; 16 MFMA ;
//       s_waitcnt vmcnt(4) ; bar
// Hazards: kt+2 k0-stages overwrite the current read buffer's k0 region, which
// is dead after P2's end barrier (ds_reads complete before MFMA before barrier).
// vmcnt(4) at tile end leaves only the 2 newest stages in flight, guaranteeing
// tile kt+1 fully landed before its P1.
#define GBAR() __builtin_amdgcn_s_barrier()

template <int WRITE_BF16>
__global__ __launch_bounds__(512, 2) void gemm256(const u16* __restrict__ A,
                                                  const u16* __restrict__ Bw,
                                                  void* __restrict__ Cv,
                                                  int M, int N, int K) {
  __shared__ u16 lds[65536];   // 128 KiB
  const int tid = threadIdx.x;
  const int lane = tid & 63;
  const int wave = tid >> 6;
  const int q4 = lane >> 4, l16 = lane & 15;
  const int wm = wave >> 2, wn = wave & 3;

  // bijective XCD swizzle (launcher guarantees nwg % 8 == 0)
  const int nwg = gridDim.x * gridDim.y;
  const int orig = blockIdx.y * gridDim.x + blockIdx.x;
  const int swz = (orig & 7) * (nwg >> 3) + (orig >> 3);
  const int bm = swz / gridDim.x, bn = swz % gridDim.x;
  const long m0 = (long)bm * 256, n0 = (long)bn * 256;

  // ---- staging addressing: thread t -> LDS linear t*16 bytes (+8192) ----
  const int srow = tid >> 2;            // 0..127  (second load: +128)
  const int slot = tid & 3;
  const int sx = (slot ^ ((srow >> 1) & 3)) * 8;   // (srow+128) gives same XOR
  const u16* Ag0 = A + (m0 + srow) * K + sx;
  const u16* Ag1 = A + (m0 + srow + 128) * K + sx;
  const u16* Bg0 = Bw + (n0 + srow) * K + sx;
  const u16* Bg1 = Bw + (n0 + srow + 128) * K + sx;
  u16* ldst = lds + tid * 8;            // u16 units

  const int nkt = K >> 6;

#define STAGE_A(bufi, kh, kt)                                  \
  do {                                                         \
    long ko = ((long)(kt) << 6) + ((kh) << 5);                 \
    u16* d = ldst + (bufi) * 32768 + (kh) * 8192;              \
    gload_lds16(Ag0 + ko, d);                                  \
    gload_lds16(Ag1 + ko, d + 4096);                           \
  } while (0)
#define STAGE_B(bufi, kh, kt)                                  \
  do {                                                         \
    long ko = ((long)(kt) << 6) + ((kh) << 5);                 \
    u16* d = ldst + (bufi) * 32768 + 16384 + (kh) * 8192;      \
    gload_lds16(Bg0 + ko, d);                                  \
    gload_lds16(Bg1 + ko, d + 4096);                           \
  } while (0)

  // fragment LDS offsets (u16 units) for kh=0; kh=1 adds 8192.
  // xr = ((row)>>1)&3 spreads the 16 l16-rows over 8 distinct 4-bank slots.
  int offA[8], offB[4];
#pragma unroll
  for (int m = 0; m < 8; m++) {
    int r = wm * 128 + m * 16 + l16;
    offA[m] = r * 32 + ((q4 ^ ((r >> 1) & 3)) << 3);
  }
#pragma unroll
  for (int n = 0; n < 4; n++) {
    int r = wn * 64 + n * 16 + l16;
    offB[n] = 16384 + r * 32 + ((q4 ^ ((r >> 1) & 3)) << 3);
  }

  f32x4 acc[8][4] = {};

  // ---- prologue: tile0 (4 stages) + tile1 k-half0 (2 stages) ----
  STAGE_A(0, 0, 0); STAGE_B(0, 0, 0); STAGE_A(0, 1, 0); STAGE_B(0, 1, 0);
  if (nkt > 1) { STAGE_A(1, 0, 1); STAGE_B(1, 0, 1); }
  asm volatile("s_waitcnt vmcnt(4)" ::: "memory");
  GBAR();

  for (int kt = 0; kt < nkt; kt++) {
    const int bo = (kt & 1) * 32768;    // current read buffer offset (u16)
    bf16x8 af[4], bfv[4];
    // ---------------- P1: kk=0, M 0-3, all N ----------------
#pragma unroll
    for (int m = 0; m < 4; m++) af[m] = *(const bf16x8*)(lds + bo + offA[m]);
#pragma unroll
    for (int n = 0; n < 4; n++) bfv[n] = *(const bf16x8*)(lds + bo + offB[n]);
    if (kt + 1 < nkt) STAGE_A((kt + 1) & 1, 1, kt + 1);
    GBAR();
    asm volatile("s_waitcnt lgkmcnt(0)" ::: "memory");
    __builtin_amdgcn_s_setprio(1);
#pragma unroll
    for (int m = 0; m < 4; m++)
#pragma unroll
      for (int n = 0; n < 4; n++)
        acc[m][n] = __builtin_amdgcn_mfma_f32_16x16x32_bf16(af[m], bfv[n], acc[m][n], 0, 0, 0);
    __builtin_amdgcn_s_setprio(0);
    GBAR();
    // ---------------- P2: kk=0, M 4-7 (reuse B frags) ----------------
#pragma unroll
    for (int m = 0; m < 4; m++) af[m] = *(const bf16x8*)(lds + bo + offA[4 + m]);
    if (kt + 1 < nkt) STAGE_B((kt + 1) & 1, 1, kt + 1);
    GBAR();
    asm volatile("s_waitcnt lgkmcnt(0)" ::: "memory");
    __builtin_amdgcn_s_setprio(1);
#pragma unroll
    for (int m = 0; m < 4; m++)
#pragma unroll
      for (int n = 0; n < 4; n++)
        acc[4 + m][n] = __builtin_amdgcn_mfma_f32_16x16x32_bf16(af[m], bfv[n], acc[4 + m][n], 0, 0, 0);
    __builtin_amdgcn_s_setprio(0);
    GBAR();
    // ---------------- P3: kk=1, M 0-3, all N ----------------
#pragma unroll
    for (int m = 0; m < 4; m++) af[m] = *(const bf16x8*)(lds + bo + 8192 + offA[m]);
#pragma unroll
    for (int n = 0; n < 4; n++) bfv[n] = *(const bf16x8*)(lds + bo + 8192 + offB[n]);
    if (kt + 2 < nkt) STAGE_A(kt & 1, 0, kt + 2);   // k0 region of this buf is dead
    GBAR();
    asm volatile("s_waitcnt lgkmcnt(0)" ::: "memory");
    __builtin_amdgcn_s_setprio(1);
#pragma unroll
    for (int m = 0; m < 4; m++)
#pragma unroll
      for (int n = 0; n < 4; n++)
        acc[m][n] = __builtin_amdgcn_mfma_f32_16x16x32_bf16(af[m], bfv[n], acc[m][n], 0, 0, 0);
    __builtin_amdgcn_s_setprio(0);
    GBAR();
    // ---------------- P4: kk=1, M 4-7 ----------------
#pragma unroll
    for (int m = 0; m < 4; m++) af[m] = *(const bf16x8*)(lds + bo + 8192 + offA[4 + m]);
    if (kt + 2 < nkt) STAGE_B(kt & 1, 0, kt + 2);
    GBAR();
    asm volatile("s_waitcnt lgkmcnt(0)" ::: "memory");
    __builtin_amdgcn_s_setprio(1);
#pragma unroll
    for (int m = 0; m < 4; m++)
#pragma unroll
      for (int n = 0; n < 4; n++)
        acc[4 + m][n] = __builtin_amdgcn_mfma_f32_16x16x32_bf16(af[m], bfv[n], acc[4 + m][n], 0, 0, 0);
    __builtin_amdgcn_s_setprio(0);
    // counted drain: leave only the 2 newest stages (kt+2 k0) in flight
    if (kt + 2 < nkt)
      asm volatile("s_waitcnt vmcnt(4)" ::: "memory");
    else
      asm volatile("s_waitcnt vmcnt(0)" ::: "memory");
    GBAR();
  }
#undef STAGE_A
#undef STAGE_B

  // ---- epilogue: C write (C/D frag: row = q4*4+r, col = l16) ----
  const long crow0 = m0 + wm * 128;
  const long ccol0 = n0 + wn * 64;
  if (WRITE_BF16) {
    u16* Cp = (u16*)Cv;
#pragma unroll
    for (int m = 0; m < 8; m++)
#pragma unroll
      for (int n = 0; n < 4; n++)
#pragma unroll
        for (int r = 0; r < 4; r++)
          Cp[(crow0 + m * 16 + q4 * 4 + r) * (long)N + ccol0 + n * 16 + l16] =
              f2bf(acc[m][n][r]);
  } else {
    float* Cp = (float*)Cv;
#pragma unroll
    for (int m = 0; m < 8; m++)
#pragma unroll
      for (int n = 0; n < 4; n++)
#pragma unroll
        for (int r = 0; r < 4; r++)
          Cp[(crow0 + m * 16 + q4 * 4 + r) * (long)N + ccol0 + n * 16 + l16] =
              acc[m][n][r];
  }
}

// ---------------- sliding-window attention: barrier-free, static softmax ----------------
// grid (tc, h, b); 4 waves; wave owns 32 q rows. No online max (inputs bounded,
// scores in log2-domain ±~10). S computed j-tile-wise (8 transient VGPR) so the
// compiler can pipeline K/V frag loads. One unsigned cmp does the whole band mask.
__global__ __launch_bounds__(256, 3) void attn_kernel(const u16* __restrict__ qkv,
                                                      const u16* __restrict__ K2,
                                                      const u16* __restrict__ V2,
                                                      u16* __restrict__ y) {
  const int tc = blockIdx.x, h = blockIdx.y, b = blockIdx.z;
  const int t0 = tc * 128;
  const int kvh = h >> 2;
  __shared__ u16 Pl[4 * 32 * 136];
  const int tid = threadIdx.x, wave = tid >> 6, lane = tid & 63;
  const int q4 = lane >> 4, l16 = lane & 15;
  u16* Pw = Pl + wave * (32 * 136);

  bf16x8 qf[2][4];
#pragma unroll
  for (int i = 0; i < 2; i++)
#pragma unroll
    for (int ks = 0; ks < 4; ks++)
      qf[i][ks] = *(const bf16x8*)(qkv +
          ((long)(b * T_ + t0 + 32 * wave + 16 * i + l16)) * 3072 + h * HD + ks * 32 + q4 * 8);

  f32x4 O[2][8] = {};
  float l_i[2][4] = {};

  const u16* Kb = K2 + (long)(b * NKV + kvh) * 524288 + lane * 8;
  const u16* Vb = V2 + (long)(b * NKV + kvh) * 524288 + lane * 8;

  int kstart = t0 - 256; if (kstart < 0) kstart = 0;
  for (int k0 = kstart; k0 <= t0; k0 += 128) {
    const u16* Kc = Kb + (long)(k0 >> 4) * 2048;     // kb0*4*512
    const u16* Vc = Vb + (long)(k0 >> 7) * 16384;    // kc*8*4*512
    const int dbase0 = t0 + 32 * wave + q4 * 4 - k0 - l16;
    // ---- S = Q K^T, tile-by-tile with prefetch; P -> wave-private LDS ----
    bf16x8 kn[4];
#pragma unroll
    for (int ks = 0; ks < 4; ks++) kn[ks] = *(const bf16x8*)(Kc + ks * 512);
#pragma unroll
    for (int j = 0; j < 8; j++) {
      bf16x8 kf[4];
#pragma unroll
      for (int ks = 0; ks < 4; ks++) kf[ks] = kn[ks];
      if (j < 7)
#pragma unroll
        for (int ks = 0; ks < 4; ks++)
          kn[ks] = *(const bf16x8*)(Kc + (j + 1) * 2048 + ks * 512);
      f32x4 s0 = {}, s1 = {};
#pragma unroll
      for (int ks = 0; ks < 4; ks++) {
        s0 = __builtin_amdgcn_mfma_f32_16x16x32_bf16(qf[0][ks], kf[ks], s0, 0, 0, 0);
        s1 = __builtin_amdgcn_mfma_f32_16x16x32_bf16(qf[1][ks], kf[ks], s1, 0, 0, 0);
      }
#pragma unroll
      for (int r = 0; r < 4; r++) {
        int d0 = dbase0 + r - 16 * j;               // q - k for i=0
        float p0 = __builtin_amdgcn_exp2f(s0[r]);
        p0 = ((unsigned)d0 <= 255u) ? p0 : 0.f;     // band mask, all chunks
        l_i[0][r] += p0;
        Pw[(q4 * 4 + r) * 136 + 16 * j + l16] = f2bf(p0);
        int d1 = d0 + 16;                            // i=1
        float p1 = __builtin_amdgcn_exp2f(s1[r]);
        p1 = ((unsigned)d1 <= 255u) ? p1 : 0.f;
        l_i[1][r] += p1;
        Pw[(16 + q4 * 4 + r) * 136 + 16 * j + l16] = f2bf(p1);
      }
    }
    // ---- O += P V (P A-frags from private LDS; V frags prefetched) ----
    bf16x8 vn = *(const bf16x8*)(Vc);
#pragma unroll
    for (int ks = 0; ks < 4; ks++) {
      bf16x8 pf0 = *(const bf16x8*)(&Pw[l16 * 136 + ks * 32 + q4 * 8]);
      bf16x8 pf1 = *(const bf16x8*)(&Pw[(16 + l16) * 136 + ks * 32 + q4 * 8]);
#pragma unroll
      for (int jd = 0; jd < 8; jd++) {
        bf16x8 vf = vn;
        if (!(ks == 3 && jd == 7)) {
          int njd = (jd == 7) ? 0 : jd + 1;
          int nks = (jd == 7) ? ks + 1 : ks;
          vn = *(const bf16x8*)(Vc + (njd * 4 + nks) * 512);
        }
        O[0][jd] = __builtin_amdgcn_mfma_f32_16x16x32_bf16(pf0, vf, O[0][jd], 0, 0, 0);
        O[1][jd] = __builtin_amdgcn_mfma_f32_16x16x32_bf16(pf1, vf, O[1][jd], 0, 0, 0);
      }
    }
  }
  // ---- finalize: reduce l across the 16-lane row groups, divide, store ----
#pragma unroll
  for (int d = 1; d < 16; d <<= 1)
#pragma unroll
    for (int i = 0; i < 2; i++)
#pragma unroll
      for (int r = 0; r < 4; r++)
        l_i[i][r] += __shfl_xor(l_i[i][r], d, 64);
#pragma unroll
  for (int i = 0; i < 2; i++)
#pragma unroll
    for (int r = 0; r < 4; r++) {
      float inv = 1.0f / l_i[i][r];
      long row = (long)(b * T_ + t0 + 32 * wave + 16 * i + q4 * 4 + r);
#pragma unroll
      for (int jd = 0; jd < 8; jd++)
        y[row * 2048 + h * HD + 16 * jd + l16] = f2bf(O[i][jd][r] * inv);
    }
}

// ---------------- launcher ----------------
extern "C" void kernel_launch(void* const* d_in, const int* in_sizes, int n_in,
                              void* d_out, int out_size, void* d_ws, size_t ws_size,
                              hipStream_t stream) {
  const float* x    = (const float*)d_in[0];
  const float* wq   = (const float*)d_in[1];
  const float* wk   = (const float*)d_in[2];
  const float* wv   = (const float*)d_in[3];
  const float* wo   = (const float*)d_in[4];
  const float* rope = (const float*)d_in[5];
  float* out = (float*)d_out;

  u16* xb   = (u16*)d_ws;                       // 8192*2048
  u16* wqkv = xb + (long)8192 * 2048;           // 3072*2048
  u16* wob  = wqkv + (long)3072 * 2048;         // 2048*2048
  u16* qkv  = wob + (long)2048 * 2048;          // 8192*3072
  u16* V2   = qkv + (long)8192 * 3072;          // 4.19M el
  u16* K2   = wqkv;                             // alias: wqkv dead after gemm1
  u16* yb   = xb;                               // reuse

  {
    long n = (long)8192 * 2048;
    cvt_f32_bf16<<<dim3((unsigned)((n / 4 + 255) / 256)), dim3(256), 0, stream>>>(x, xb, (int)n);
    n = (long)2048 * 2048;
    cvt_f32_bf16<<<dim3((unsigned)((n / 4 + 255) / 256)), dim3(256), 0, stream>>>(wq, wqkv, (int)n);
    n = (long)512 * 2048;
    cvt_f32_bf16<<<dim3((unsigned)((n / 4 + 255) / 256)), dim3(256), 0, stream>>>(
        wk, wqkv + (long)2048 * 2048, (int)n);
    cvt_f32_bf16<<<dim3((unsigned)((n / 4 + 255) / 256)), dim3(256), 0, stream>>>(
        wv, wqkv + (long)2048 * 2048 + (long)512 * 2048, (int)n);
    n = (long)2048 * 2048;
    cvt_f32_bf16<<<dim3((unsigned)((n / 4 + 255) / 256)), dim3(256), 0, stream>>>(wo, wob, (int)n);
  }

  gemm256<1><<<dim3(3072 / 256, 8192 / 256), dim3(512), 0, stream>>>(
      xb, wqkv, (void*)qkv, 8192, 3072, 2048);

  long npairs = (long)B_ * T_ * (NH + NKV) * (HD / 2);
  rope_kernel<<<dim3((unsigned)((npairs + 255) / 256)), dim3(256), 0, stream>>>(qkv, rope);

  krearr<<<dim3(2048), dim3(256), 0, stream>>>(qkv, K2);
  vrearr<<<dim3(2048), dim3(256), 0, stream>>>(qkv, V2);

  attn_kernel<<<dim3(T_ / 128, NH, B_), dim3(256), 0, stream>>>(qkv, K2, V2, yb);

  gemm256<0><<<dim3(2048 / 256, 8192 / 256), dim3(512), 0, stream>>>(
      yb, wob, (void*)out, 8192, 2048, 2048);
}

// Round 2
// 446.652 us; speedup vs baseline: 1.1556x; 1.0234x over previous
//
#include <hip/hip_runtime.h>
#include <stdint.h>

typedef unsigned short u16;
typedef __attribute__((ext_vector_type(8))) short bf16x8;      // 8 bf16 = 4 VGPRs
typedef __attribute__((ext_vector_type(8))) unsigned short u16x8;
typedef __attribute__((ext_vector_type(4))) float f32x4;

#define B_  2
#define T_  4096
#define C_  2048
#define NH  16
#define NKV 4
#define HD  128

__device__ __forceinline__ u16 f2bf(float f) {
  union { float f; uint32_t u; } v; v.f = f;
  uint32_t u = v.u;
  u += 0x7fffu + ((u >> 16) & 1u);   // RNE
  return (u16)(u >> 16);
}
__device__ __forceinline__ float bf2f(u16 h) {
  union { uint32_t u; float f; } v; v.u = ((uint32_t)h) << 16;
  return v.f;
}

__device__ __forceinline__ void gload_lds16(const u16* g, u16* l) {
  __builtin_amdgcn_global_load_lds(
      (const __attribute__((address_space(1))) void*)g,
      (__attribute__((address_space(3))) void*)l, 16, 0, 0);
}

// ---------------- f32 -> bf16 convert ----------------
__global__ void cvt_f32_bf16(const float* __restrict__ src, u16* __restrict__ dst, int n) {
  int i = (blockIdx.x * blockDim.x + threadIdx.x) * 4;
  if (i >= n) return;
  float4 v = *(const float4*)(src + i);
  ushort4 o;
  o.x = f2bf(v.x); o.y = f2bf(v.y); o.z = f2bf(v.z); o.w = f2bf(v.w);
  *(ushort4*)(dst + i) = o;
}

// ---------------- in-place RoPE on qkv [B*T][3072]; Q pre-scaled by 1/sqrt(D)*log2e ----------------
__global__ void rope_kernel(u16* __restrict__ qkv, const float* __restrict__ cache) {
  const int PH = (NH + NKV) * (HD / 2);   // 1280 pairs per row
  long idx = (long)blockIdx.x * blockDim.x + threadIdx.x;
  if (idx >= (long)B_ * T_ * PH) return;
  int row = (int)(idx / PH);
  int rem = (int)(idx % PH);
  int hh = rem >> 6;
  int i  = rem & 63;
  int t  = row & (T_ - 1);
  float sc = (hh < NH) ? 0.1275174315f : 1.0f;   // q heads: fold scale*log2(e)
  float c = cache[t * 128 + 2 * i] * sc;
  float s = cache[t * 128 + 2 * i + 1] * sc;
  u16* p = qkv + (long)row * 3072 + hh * HD + 2 * i;
  float x0 = bf2f(p[0]), x1 = bf2f(p[1]);
  p[0] = f2bf(x0 * c - x1 * s);
  p[1] = f2bf(x0 * s + x1 * c);
}

// ---------------- K rearrange: frag-linear layout ----------------
// K2[bk][kb=key/16][ks=d/32][q4][l16=key%16][e=d%8]
__global__ void krearr(const u16* __restrict__ qkv, u16* __restrict__ K2) {
  int gid = blockIdx.x * 256 + threadIdx.x;
  int r = gid & 65535, bk = gid >> 16;
  int l16 = r & 15, q4 = (r >> 4) & 3, ks = (r >> 6) & 3, kb = r >> 8;
  int bb = bk >> 2, kv = bk & 3;
  const u16* src = qkv + ((long)(bb * T_ + kb * 16 + l16)) * 3072 + 2048 + kv * HD +
                   ks * 32 + q4 * 8;
  *(u16x8*)(K2 + (long)bk * 524288 + (long)r * 8) = *(const u16x8*)src;
}

// ---------------- V rearrange: frag-linear transposed layout ----------------
// V2[bk][kc=key/128][jd=d/16][ks=(key%128)/32][q4][l16=d%16][e=key%8]
__global__ void vrearr(const u16* __restrict__ qkv, u16* __restrict__ V2) {
  int gid = blockIdx.x * 256 + threadIdx.x;
  int r = gid & 65535, bk = gid >> 16;
  int l16 = r & 15, q4 = (r >> 4) & 3, ks = (r >> 6) & 3, jd = (r >> 8) & 7, kc = r >> 11;
  int bb = bk >> 2, kv = bk & 3;
  int key0 = kc * 128 + ks * 32 + q4 * 8;
  int d = jd * 16 + l16;
  const u16* src = qkv + ((long)(bb * T_ + key0)) * 3072 + 2560 + kv * HD + d;
  u16x8 v;
#pragma unroll
  for (int e = 0; e < 8; e++) v[e] = src[(long)e * 3072];
  *(u16x8*)(V2 + (long)bk * 524288 + (long)r * 8) = v;
}

// ---------------- bf16 GEMM: C[M][N] = A[M][K] * B[N][K]^T ----------------
// 256x256 tile, BK=64, 8 waves (2M x 4N), double-buffered 128 KiB LDS.
// READ-AHEAD pipeline, 2 barriers per K-tile:
//   each phase's ds_reads are issued UNDER the previous phase's MFMA burst, so
//   every lgkmcnt(0) wait is preceded by a ~620-cycle MFMA burst that hides the
//   LDS latency. Only the tile-first read cluster (R1) is cold: it must sit
//   after the tile barrier, because stage visibility is per-wave (vmcnt) and
//   only a barrier makes OTHER waves' global_load_lds stages globally visible.
//
// Steady-state iteration kt (queue invariant at entry: 4 outstanding loads =
// kt+1's k0 half-stages, issued last iteration):
//   R1: afX<-A[0..3]k0, bvA<-B[0..3]k0 (8 ds)  ; S_A(kt+1,k1)
//   lgkm(0) ; R2: afY<-A[4..7]k0 (4 ds) ; MFMA16 acc[0..3]
//   S_B(kt+1,k1) ; lgkm(0) ; R3: afX<-A[0..3]k1, bvB<-B k1 (8 ds) ; MFMA16 acc[4..7]
//   BAR   (all waves' k0 reads complete -> k0 region reusable)
//   S_A(kt+2,k0 into cur) ; lgkm(0) ; R4: afY<-A[4..7]k1 (4 ds) ; MFMA16 acc[0..3]
//   S_B(kt+2,k0) ; lgkm(0) ; MFMA16 acc[4..7]
//   vmcnt(4)  (first 8 of 12 outstanding = ALL kt+1 stages landed) ; BAR
// Hazards re-verified: k1 stages (P1/P2) write buf[next] k1, last read two
// tiles ago, guarded by previous end-BAR; k0 reuse stages guarded by mid-BAR;
// tail uses vmcnt(0) when kt+2>=nkt so the final tiles are fully drained.
#define GBAR() __builtin_amdgcn_s_barrier()
#define LGKM0() do { asm volatile("s_waitcnt lgkmcnt(0)" ::: "memory"); \
                     __builtin_amdgcn_sched_barrier(0); } while (0)

template <int WRITE_BF16>
__global__ __launch_bounds__(512, 2) void gemm256(const u16* __restrict__ A,
                                                  const u16* __restrict__ Bw,
                                                  void* __restrict__ Cv,
                                                  int M, int N, int K) {
  __shared__ u16 lds[65536];   // 128 KiB
  const int tid = threadIdx.x;
  const int lane = tid & 63;
  const int wave = tid >> 6;
  const int q4 = lane >> 4, l16 = lane & 15;
  const int wm = wave >> 2, wn = wave & 3;

  // bijective XCD swizzle (launcher guarantees nwg % 8 == 0)
  const int nwg = gridDim.x * gridDim.y;
  const int orig = blockIdx.y * gridDim.x + blockIdx.x;
  const int swz = (orig & 7) * (nwg >> 3) + (orig >> 3);
  const int bm = swz / gridDim.x, bn = swz % gridDim.x;
  const long m0 = (long)bm * 256, n0 = (long)bn * 256;

  // ---- staging addressing: thread t -> LDS linear t*16 bytes (+8192) ----
  const int srow = tid >> 2;            // 0..127  (second load: +128)
  const int slot = tid & 3;
  const int sx = (slot ^ ((srow >> 1) & 3)) * 8;   // (srow+128) gives same XOR
  const u16* Ag0 = A + (m0 + srow) * K + sx;
  const u16* Ag1 = A + (m0 + srow + 128) * K + sx;
  const u16* Bg0 = Bw + (n0 + srow) * K + sx;
  const u16* Bg1 = Bw + (n0 + srow + 128) * K + sx;
  u16* ldst = lds + tid * 8;            // u16 units

  const int nkt = K >> 6;

#define STAGE_A(bufi, kh, kt)                                  \
  do {                                                         \
    long ko = ((long)(kt) << 6) + ((kh) << 5);                 \
    u16* d = ldst + (bufi) * 32768 + (kh) * 8192;              \
    gload_lds16(Ag0 + ko, d);                                  \
    gload_lds16(Ag1 + ko, d + 4096);                           \
  } while (0)
#define STAGE_B(bufi, kh, kt)                                  \
  do {                                                         \
    long ko = ((long)(kt) << 6) + ((kh) << 5);                 \
    u16* d = ldst + (bufi) * 32768 + 16384 + (kh) * 8192;      \
    gload_lds16(Bg0 + ko, d);                                  \
    gload_lds16(Bg1 + ko, d + 4096);                           \
  } while (0)

  // fragment LDS offsets (u16 units) for kh=0; kh=1 adds 8192.
  int offA[8], offB[4];
#pragma unroll
  for (int m = 0; m < 8; m++) {
    int r = wm * 128 + m * 16 + l16;
    offA[m] = r * 32 + ((q4 ^ ((r >> 1) & 3)) << 3);
  }
#pragma unroll
  for (int n = 0; n < 4; n++) {
    int r = wn * 64 + n * 16 + l16;
    offB[n] = 16384 + r * 32 + ((q4 ^ ((r >> 1) & 3)) << 3);
  }

  f32x4 acc[8][4] = {};

  // ---- prologue: tile0 (4 half-stages) + tile1 k0 (2 half-stages) ----
  STAGE_A(0, 0, 0); STAGE_B(0, 0, 0); STAGE_A(0, 1, 0); STAGE_B(0, 1, 0);
  if (nkt > 1) {
    STAGE_A(1, 0, 1); STAGE_B(1, 0, 1);
    asm volatile("s_waitcnt vmcnt(4)" ::: "memory");
  } else {
    asm volatile("s_waitcnt vmcnt(0)" ::: "memory");
  }
  GBAR();

  bf16x8 afX[4], afY[4], bvA[4], bvB[4];
  for (int kt = 0; kt < nkt; kt++) {
    const int bo = (kt & 1) * 32768;    // current read buffer offset (u16)
    // ---- P1: R1 (cold) ; stage A-k1 ; wait ; R2 under MFMA ----
#pragma unroll
    for (int m = 0; m < 4; m++) afX[m] = *(const bf16x8*)(lds + bo + offA[m]);
#pragma unroll
    for (int n = 0; n < 4; n++) bvA[n] = *(const bf16x8*)(lds + bo + offB[n]);
    if (kt + 1 < nkt) STAGE_A((kt + 1) & 1, 1, kt + 1);
    LGKM0();
#pragma unroll
    for (int m = 0; m < 4; m++) afY[m] = *(const bf16x8*)(lds + bo + offA[4 + m]);
    __builtin_amdgcn_s_setprio(1);
#pragma unroll
    for (int m = 0; m < 4; m++)
#pragma unroll
      for (int n = 0; n < 4; n++)
        acc[m][n] = __builtin_amdgcn_mfma_f32_16x16x32_bf16(afX[m], bvA[n], acc[m][n], 0, 0, 0);
    __builtin_amdgcn_s_setprio(0);
    // ---- P2: stage B-k1 ; wait R2 ; R3 under MFMA ; mid-BAR ----
    if (kt + 1 < nkt) STAGE_B((kt + 1) & 1, 1, kt + 1);
    LGKM0();
#pragma unroll
    for (int m = 0; m < 4; m++) afX[m] = *(const bf16x8*)(lds + bo + 8192 + offA[m]);
#pragma unroll
    for (int n = 0; n < 4; n++) bvB[n] = *(const bf16x8*)(lds + bo + 8192 + offB[n]);
    __builtin_amdgcn_s_setprio(1);
#pragma unroll
    for (int m = 0; m < 4; m++)
#pragma unroll
      for (int n = 0; n < 4; n++)
        acc[4 + m][n] = __builtin_amdgcn_mfma_f32_16x16x32_bf16(afY[m], bvA[n], acc[4 + m][n], 0, 0, 0);
    __builtin_amdgcn_s_setprio(0);
    GBAR();                              // k0 globally consumed -> reusable
    // ---- P3: stage A-k0(kt+2) into cur ; wait R3 ; R4 under MFMA ----
    if (kt + 2 < nkt) STAGE_A(kt & 1, 0, kt + 2);
    LGKM0();
#pragma unroll
    for (int m = 0; m < 4; m++) afY[m] = *(const bf16x8*)(lds + bo + 8192 + offA[4 + m]);
    __builtin_amdgcn_s_setprio(1);
#pragma unroll
    for (int m = 0; m < 4; m++)
#pragma unroll
      for (int n = 0; n < 4; n++)
        acc[m][n] = __builtin_amdgcn_mfma_f32_16x16x32_bf16(afX[m], bvB[n], acc[m][n], 0, 0, 0);
    __builtin_amdgcn_s_setprio(0);
    // ---- P4: stage B-k0(kt+2) ; wait R4 ; MFMA ; counted vmcnt ; BAR ----
    if (kt + 2 < nkt) STAGE_B(kt & 1, 0, kt + 2);
    LGKM0();
    __builtin_amdgcn_s_setprio(1);
#pragma unroll
    for (int m = 0; m < 4; m++)
#pragma unroll
      for (int n = 0; n < 4; n++)
        acc[4 + m][n] = __builtin_amdgcn_mfma_f32_16x16x32_bf16(afY[m], bvB[n], acc[4 + m][n], 0, 0, 0);
    __builtin_amdgcn_s_setprio(0);
    if (kt + 2 < nkt)
      asm volatile("s_waitcnt vmcnt(4)" ::: "memory");
    else
      asm volatile("s_waitcnt vmcnt(0)" ::: "memory");
    GBAR();
  }
#undef STAGE_A
#undef STAGE_B

  // ---- epilogue: C write (C/D frag: row = q4*4+r, col = l16) ----
  const long crow0 = m0 + wm * 128;
  const long ccol0 = n0 + wn * 64;
  if (WRITE_BF16) {
    u16* Cp = (u16*)Cv;
#pragma unroll
    for (int m = 0; m < 8; m++)
#pragma unroll
      for (int n = 0; n < 4; n++)
#pragma unroll
        for (int r = 0; r < 4; r++)
          Cp[(crow0 + m * 16 + q4 * 4 + r) * (long)N + ccol0 + n * 16 + l16] =
              f2bf(acc[m][n][r]);
  } else {
    float* Cp = (float*)Cv;
#pragma unroll
    for (int m = 0; m < 8; m++)
#pragma unroll
      for (int n = 0; n < 4; n++)
#pragma unroll
        for (int r = 0; r < 4; r++)
          Cp[(crow0 + m * 16 + q4 * 4 + r) * (long)N + ccol0 + n * 16 + l16] =
              acc[m][n][r];
  }
}

// ---------------- sliding-window attention: barrier-free, static softmax ----------------
__global__ __launch_bounds__(256, 3) void attn_kernel(const u16* __restrict__ qkv,
                                                      const u16* __restrict__ K2,
                                                      const u16* __restrict__ V2,
                                                      u16* __restrict__ y) {
  const int tc = blockIdx.x, h = blockIdx.y, b = blockIdx.z;
  const int t0 = tc * 128;
  const int kvh = h >> 2;
  __shared__ u16 Pl[4 * 32 * 136];
  const int tid = threadIdx.x, wave = tid >> 6, lane = tid & 63;
  const int q4 = lane >> 4, l16 = lane & 15;
  u16* Pw = Pl + wave * (32 * 136);

  bf16x8 qf[2][4];
#pragma unroll
  for (int i = 0; i < 2; i++)
#pragma unroll
    for (int ks = 0; ks < 4; ks++)
      qf[i][ks] = *(const bf16x8*)(qkv +
          ((long)(b * T_ + t0 + 32 * wave + 16 * i + l16)) * 3072 + h * HD + ks * 32 + q4 * 8);

  f32x4 O[2][8] = {};
  float l_i[2][4] = {};

  const u16* Kb = K2 + (long)(b * NKV + kvh) * 524288 + lane * 8;
  const u16* Vb = V2 + (long)(b * NKV + kvh) * 524288 + lane * 8;

  int kstart = t0 - 256; if (kstart < 0) kstart = 0;
  for (int k0 = kstart; k0 <= t0; k0 += 128) {
    const u16* Kc = Kb + (long)(k0 >> 4) * 2048;     // kb0*4*512
    const u16* Vc = Vb + (long)(k0 >> 7) * 16384;    // kc*8*4*512
    const int dbase0 = t0 + 32 * wave + q4 * 4 - k0 - l16;
    // ---- S = Q K^T, tile-by-tile with prefetch; P -> wave-private LDS ----
    bf16x8 kn[4];
#pragma unroll
    for (int ks = 0; ks < 4; ks++) kn[ks] = *(const bf16x8*)(Kc + ks * 512);
#pragma unroll
    for (int j = 0; j < 8; j++) {
      bf16x8 kf[4];
#pragma unroll
      for (int ks = 0; ks < 4; ks++) kf[ks] = kn[ks];
      if (j < 7)
#pragma unroll
        for (int ks = 0; ks < 4; ks++)
          kn[ks] = *(const bf16x8*)(Kc + (j + 1) * 2048 + ks * 512);
      f32x4 s0 = {}, s1 = {};
#pragma unroll
      for (int ks = 0; ks < 4; ks++) {
        s0 = __builtin_amdgcn_mfma_f32_16x16x32_bf16(qf[0][ks], kf[ks], s0, 0, 0, 0);
        s1 = __builtin_amdgcn_mfma_f32_16x16x32_bf16(qf[1][ks], kf[ks], s1, 0, 0, 0);
      }
#pragma unroll
      for (int r = 0; r < 4; r++) {
        int d0 = dbase0 + r - 16 * j;               // q - k for i=0
        float p0 = __builtin_amdgcn_exp2f(s0[r]);
        p0 = ((unsigned)d0 <= 255u) ? p0 : 0.f;     // band mask, all chunks
        l_i[0][r] += p0;
        Pw[(q4 * 4 + r) * 136 + 16 * j + l16] = f2bf(p0);
        int d1 = d0 + 16;                            // i=1
        float p1 = __builtin_amdgcn_exp2f(s1[r]);
        p1 = ((unsigned)d1 <= 255u) ? p1 : 0.f;
        l_i[1][r] += p1;
        Pw[(16 + q4 * 4 + r) * 136 + 16 * j + l16] = f2bf(p1);
      }
    }
    // ---- O += P V (P A-frags from private LDS; V frags prefetched) ----
    bf16x8 vn = *(const bf16x8*)(Vc);
#pragma unroll
    for (int ks = 0; ks < 4; ks++) {
      bf16x8 pf0 = *(const bf16x8*)(&Pw[l16 * 136 + ks * 32 + q4 * 8]);
      bf16x8 pf1 = *(const bf16x8*)(&Pw[(16 + l16) * 136 + ks * 32 + q4 * 8]);
#pragma unroll
      for (int jd = 0; jd < 8; jd++) {
        bf16x8 vf = vn;
        if (!(ks == 3 && jd == 7)) {
          int njd = (jd == 7) ? 0 : jd + 1;
          int nks = (jd == 7) ? ks + 1 : ks;
          vn = *(const bf16x8*)(Vc + (njd * 4 + nks) * 512);
        }
        O[0][jd] = __builtin_amdgcn_mfma_f32_16x16x32_bf16(pf0, vf, O[0][jd], 0, 0, 0);
        O[1][jd] = __builtin_amdgcn_mfma_f32_16x16x32_bf16(pf1, vf, O[1][jd], 0, 0, 0);
      }
    }
  }
  // ---- finalize: reduce l across the 16-lane row groups, divide, store ----
#pragma unroll
  for (int d = 1; d < 16; d <<= 1)
#pragma unroll
    for (int i = 0; i < 2; i++)
#pragma unroll
      for (int r = 0; r < 4; r++)
        l_i[i][r] += __shfl_xor(l_i[i][r], d, 64);
#pragma unroll
  for (int i = 0; i < 2; i++)
#pragma unroll
    for (int r = 0; r < 4; r++) {
      float inv = 1.0f / l_i[i][r];
      long row = (long)(b * T_ + t0 + 32 * wave + 16 * i + q4 * 4 + r);
#pragma unroll
      for (int jd = 0; jd < 8; jd++)
        y[row * 2048 + h * HD + 16 * jd + l16] = f2bf(O[i][jd][r] * inv);
    }
}

// ---------------- launcher ----------------
extern "C" void kernel_launch(void* const* d_in, const int* in_sizes, int n_in,
                              void* d_out, int out_size, void* d_ws, size_t ws_size,
                              hipStream_t stream) {
  const float* x    = (const float*)d_in[0];
  const float* wq   = (const float*)d_in[1];
  const float* wk   = (const float*)d_in[2];
  const float* wv   = (const float*)d_in[3];
  const float* wo   = (const float*)d_in[4];
  const float* rope = (const float*)d_in[5];
  float* out = (float*)d_out;

  u16* xb   = (u16*)d_ws;                       // 8192*2048
  u16* wqkv = xb + (long)8192 * 2048;           // 3072*2048
  u16* wob  = wqkv + (long)3072 * 2048;         // 2048*2048
  u16* qkv  = wob + (long)2048 * 2048;          // 8192*3072
  u16* V2   = qkv + (long)8192 * 3072;          // 4.19M el
  u16* K2   = wqkv;                             // alias: wqkv dead after gemm1
  u16* yb   = xb;                               // reuse

  {
    long n = (long)8192 * 2048;
    cvt_f32_bf16<<<dim3((unsigned)((n / 4 + 255) / 256)), dim3(256), 0, stream>>>(x, xb, (int)n);
    n = (long)2048 * 2048;
    cvt_f32_bf16<<<dim3((unsigned)((n / 4 + 255) / 256)), dim3(256), 0, stream>>>(wq, wqkv, (int)n);
    n = (long)512 * 2048;
    cvt_f32_bf16<<<dim3((unsigned)((n / 4 + 255) / 256)), dim3(256), 0, stream>>>(
        wk, wqkv + (long)2048 * 2048, (int)n);
    cvt_f32_bf16<<<dim3((unsigned)((n / 4 + 255) / 256)), dim3(256), 0, stream>>>(
        wv, wqkv + (long)2048 * 2048 + (long)512 * 2048, (int)n);
    n = (long)2048 * 2048;
    cvt_f32_bf16<<<dim3((unsigned)((n / 4 + 255) / 256)), dim3(256), 0, stream>>>(wo, wob, (int)n);
  }

  gemm256<1><<<dim3(3072 / 256, 8192 / 256), dim3(512), 0, stream>>>(
      xb, wqkv, (void*)qkv, 8192, 3072, 2048);

  long npairs = (long)B_ * T_ * (NH + NKV) * (HD / 2);
  rope_kernel<<<dim3((unsigned)((npairs + 255) / 256)), dim3(256), 0, stream>>>(qkv, rope);

  krearr<<<dim3(2048), dim3(256), 0, stream>>>(qkv, K2);
  vrearr<<<dim3(2048), dim3(256), 0, stream>>>(qkv, V2);

  attn_kernel<<<dim3(T_ / 128, NH, B_), dim3(256), 0, stream>>>(qkv, K2, V2, yb);

  gemm256<0><<<dim3(2048 / 256, 8192 / 256), dim3(512), 0, stream>>>(
      yb, wob, (void*)out, 8192, 2048, 2048);
}